// Round 5
// baseline (104.048 us; speedup 1.0000x reference)
//
#include <hip/hip_runtime.h>

#define SEQ 8
#define DIM 16
#define FF 32
#define VOCAB 256

typedef float f2 __attribute__((ext_vector_type(2)));

__device__ __forceinline__ f2 v2fma(f2 a, f2 b, f2 c) {
    return __builtin_elementwise_fma(a, b, c);
}
__device__ __forceinline__ f2 splat(float s) { f2 r; r.x = s; r.y = s; return r; }

// ds_swizzle XOR butterfly on a float (src_lane = lane ^ T, T<8)
#define SWZF(val, imm) __int_as_float(__builtin_amdgcn_ds_swizzle(__float_as_int(val), (imm)))

// ---------------------------------------------------------------------------
// Body: 2 rows per thread (rowA = blk*256+tid, rowB = rowA + nrows/2), all
// state packed in float2 -> v_pk_fma_f32, halved scalar-load traffic, 2-wide
// ILP in every chain. 8 rows of an item sit in 8 consecutive lanes; K/V
// exchanged via ds_swizzle XOR (no LDS, no barriers).
// ---------------------------------------------------------------------------
__global__ __launch_bounds__(256, 2) void body_kernel(
    const int* __restrict__ x,
    const float* __restrict__ token_embed,
    const float* __restrict__ pos_embed,
    const float* __restrict__ Wq, const float* __restrict__ bq,
    const float* __restrict__ Wk, const float* __restrict__ bk,
    const float* __restrict__ Wv, const float* __restrict__ bv,
    const float* __restrict__ Wo, const float* __restrict__ bo,
    const float* __restrict__ W1, const float* __restrict__ b1,
    const float* __restrict__ W2, const float* __restrict__ b2,
    float* __restrict__ xout, int half_rows)
{
    const int tid = threadIdx.x;
    const int n = tid & 7;                                   // seq position
    const size_t rowA = (size_t)blockIdx.x * 256 + tid;
    const size_t rowB = rowA + half_rows;                    // half_rows % 8 == 0

    // ---------------- embedding + positional ----------------
    f2 X[DIM];
    {
        const int idxA = x[rowA];
        const int idxB = x[rowB];
        const float4* teA = (const float4*)(token_embed + (size_t)idxA * DIM);
        const float4* teB = (const float4*)(token_embed + (size_t)idxB * DIM);
        const float4* pe  = (const float4*)(pos_embed + n * DIM);
        #pragma unroll
        for (int j = 0; j < 4; ++j) {
            float4 a = teA[j];
            float4 b = teB[j];
            float4 p = pe[j];
            X[4*j+0].x = a.x + p.x; X[4*j+0].y = b.x + p.x;
            X[4*j+1].x = a.y + p.y; X[4*j+1].y = b.y + p.y;
            X[4*j+2].x = a.z + p.z; X[4*j+2].y = b.z + p.z;
            X[4*j+3].x = a.w + p.w; X[4*j+3].y = b.w + p.w;
        }
    }

    // ---------------- QKV: outer-product over d, packed acc chains ----------
    f2 q[DIM], k[DIM], v[DIM];
    #pragma unroll
    for (int e = 0; e < DIM; ++e) {
        q[e] = splat(bq[e]); k[e] = splat(bk[e]); v[e] = splat(bv[e]);
    }
    #pragma unroll
    for (int d = 0; d < DIM; ++d) {
        const f2 xd = X[d];
        #pragma unroll
        for (int e = 0; e < DIM; ++e) {
            q[e] = v2fma(xd, splat(Wq[d * DIM + e]), q[e]);
            k[e] = v2fma(xd, splat(Wk[d * DIM + e]), k[e]);
            v[e] = v2fma(xd, splat(Wv[d * DIM + e]), v[e]);
        }
    }

    // ---------------- attention scores via XOR butterfly ----------------
    f2 sc[SEQ];
    {
        f2 acc = splat(0.f);
        #pragma unroll
        for (int d = 0; d < DIM; ++d) acc = v2fma(q[d], k[d], acc);
        sc[0] = acc * 0.25f;
    }
    #define SCORE_PHASE(T, IMM)                                    \
    {                                                              \
        f2 acc = splat(0.f);                                       \
        _Pragma("unroll")                                          \
        for (int d = 0; d < DIM; ++d) {                            \
            f2 ks; ks.x = SWZF(k[d].x, IMM); ks.y = SWZF(k[d].y, IMM); \
            acc = v2fma(q[d], ks, acc);                            \
        }                                                          \
        sc[T] = acc * 0.25f;                                       \
    }
    SCORE_PHASE(1, 0x041F)
    SCORE_PHASE(2, 0x081F)
    SCORE_PHASE(3, 0x0C1F)
    SCORE_PHASE(4, 0x101F)
    SCORE_PHASE(5, 0x141F)
    SCORE_PHASE(6, 0x181F)
    SCORE_PHASE(7, 0x1C1F)
    #undef SCORE_PHASE

    // ---------------- softmax over 8 scores (per lane, per component) -------
    f2 mx = sc[0];
    #pragma unroll
    for (int m = 1; m < SEQ; ++m) mx = __builtin_elementwise_max(mx, sc[m]);
    f2 w[SEQ];
    f2 sum = splat(0.f);
    #pragma unroll
    for (int m = 0; m < SEQ; ++m) {
        f2 e;
        e.x = __expf(sc[m].x - mx.x);
        e.y = __expf(sc[m].y - mx.y);
        w[m] = e;
        sum += e;
    }
    f2 inv; inv.x = 1.0f / sum.x; inv.y = 1.0f / sum.y;
    #pragma unroll
    for (int m = 0; m < SEQ; ++m) w[m] *= inv;

    // ---------------- PV via XOR butterfly ----------------
    f2 at[DIM];
    #pragma unroll
    for (int d = 0; d < DIM; ++d) at[d] = w[0] * v[d];
    #define PV_PHASE(T, IMM)                                       \
    {                                                              \
        const f2 wt = w[T];                                        \
        _Pragma("unroll")                                          \
        for (int d = 0; d < DIM; ++d) {                            \
            f2 vs; vs.x = SWZF(v[d].x, IMM); vs.y = SWZF(v[d].y, IMM); \
            at[d] = v2fma(wt, vs, at[d]);                          \
        }                                                          \
    }
    PV_PHASE(1, 0x041F)
    PV_PHASE(2, 0x081F)
    PV_PHASE(3, 0x0C1F)
    PV_PHASE(4, 0x101F)
    PV_PHASE(5, 0x141F)
    PV_PHASE(6, 0x181F)
    PV_PHASE(7, 0x1C1F)
    #undef PV_PHASE

    // ---------------- O projection + residual ----------------
    f2 X1[DIM];
    #pragma unroll
    for (int e = 0; e < DIM; ++e) X1[e] = X[e] + splat(bo[e]);
    #pragma unroll
    for (int d = 0; d < DIM; ++d) {
        const f2 ad = at[d];
        #pragma unroll
        for (int e = 0; e < DIM; ++e)
            X1[e] = v2fma(ad, splat(Wo[d * DIM + e]), X1[e]);
    }

    // ---------------- FFN + residual ----------------
    f2 h[FF];
    #pragma unroll
    for (int f = 0; f < FF; ++f) h[f] = splat(b1[f]);
    #pragma unroll
    for (int d = 0; d < DIM; ++d) {
        const f2 xd = X1[d];
        #pragma unroll
        for (int f = 0; f < FF; ++f)
            h[f] = v2fma(xd, splat(W1[d * FF + f]), h[f]);
    }
    #pragma unroll
    for (int f = 0; f < FF; ++f) h[f] = __builtin_elementwise_max(h[f], splat(0.f));

    f2 X2[DIM];
    #pragma unroll
    for (int e = 0; e < DIM; ++e) X2[e] = X1[e] + splat(b2[e]);
    #pragma unroll
    for (int f = 0; f < FF; ++f) {
        const f2 hf = h[f];
        #pragma unroll
        for (int e = 0; e < DIM; ++e)
            X2[e] = v2fma(hf, splat(W2[f * DIM + e]), X2[e]);
    }

    // ---------------- write both X2 rows ----------------
    {
        float4* dA = (float4*)(xout + rowA * DIM);
        float4* dB = (float4*)(xout + rowB * DIM);
        #pragma unroll
        for (int j = 0; j < 4; ++j) {
            float4 a, b;
            a.x = X2[4*j+0].x; a.y = X2[4*j+1].x; a.z = X2[4*j+2].x; a.w = X2[4*j+3].x;
            b.x = X2[4*j+0].y; b.y = X2[4*j+1].y; b.z = X2[4*j+2].y; b.w = X2[4*j+3].y;
            dA[j] = a;
            dB[j] = b;
        }
    }
}

// ---------------------------------------------------------------------------
// Head: vocab GEMM [R,16] @ [16,256] + bias. Wave-uniform s_load of the X row,
// 1 col/lane, coalesced 256B stores. ~write-BW-bound (~49us).
// ---------------------------------------------------------------------------
#define ROWS_PER_BLOCK 32

__global__ __launch_bounds__(256) void head_kernel(
    const float* __restrict__ xin,
    const float* __restrict__ Wh,
    const float* __restrict__ bh,
    float* __restrict__ out)
{
    const int tid = threadIdx.x;
    const int col = tid;
    float wh[DIM];
    #pragma unroll
    for (int d = 0; d < DIM; ++d) wh[d] = Wh[d * VOCAB + col];
    const float bhv = bh[col];

    const size_t row0 = (size_t)blockIdx.x * ROWS_PER_BLOCK;
    #pragma unroll 4
    for (int r = 0; r < ROWS_PER_BLOCK; ++r) {
        const float* xr = xin + (row0 + r) * DIM;  // wave-uniform address
        float acc = bhv;
        #pragma unroll
        for (int d = 0; d < DIM; ++d) acc += xr[d] * wh[d];
        out[(row0 + r) * VOCAB + col] = acc;
    }
}

// ---------------------------------------------------------------------------
// Fallback (ws too small): single-pass per-row body + per-column head.
// ---------------------------------------------------------------------------
#define ITEMS_PER_BLOCK 32
#define ITEM_STRIDE 136

__global__ __launch_bounds__(256) void fused_fallback_kernel(
    const int* __restrict__ x,
    const float* __restrict__ token_embed,
    const float* __restrict__ pos_embed,
    const float* __restrict__ Wq, const float* __restrict__ bq,
    const float* __restrict__ Wk, const float* __restrict__ bk,
    const float* __restrict__ Wv, const float* __restrict__ bv,
    const float* __restrict__ Wo, const float* __restrict__ bo,
    const float* __restrict__ W1, const float* __restrict__ b1,
    const float* __restrict__ W2, const float* __restrict__ b2,
    const float* __restrict__ Wh, const float* __restrict__ bh,
    float* __restrict__ out)
{
    __shared__ float sK[ITEMS_PER_BLOCK * ITEM_STRIDE];
    __shared__ float sV[ITEMS_PER_BLOCK * ITEM_STRIDE];

    const int tid = threadIdx.x;
    const int i = tid >> 3;
    const int n = tid & 7;
    const int b = blockIdx.x * ITEMS_PER_BLOCK + i;

    float X[DIM];
    {
        const int idx = x[b * SEQ + n];
        const float4* te = (const float4*)(token_embed + idx * DIM);
        const float4* pe = (const float4*)(pos_embed + n * DIM);
        #pragma unroll
        for (int j = 0; j < 4; ++j) {
            float4 a = te[j];
            float4 p = pe[j];
            X[4*j+0] = a.x + p.x; X[4*j+1] = a.y + p.y;
            X[4*j+2] = a.z + p.z; X[4*j+3] = a.w + p.w;
        }
    }

    float Q[DIM], Kr[DIM], Vr[DIM];
    #pragma unroll
    for (int e = 0; e < DIM; ++e) {
        float qq = bq[e], kk = bk[e], vv = bv[e];
        #pragma unroll
        for (int d = 0; d < DIM; ++d) {
            qq += X[d] * Wq[d * DIM + e];
            kk += X[d] * Wk[d * DIM + e];
            vv += X[d] * Wv[d * DIM + e];
        }
        Q[e] = qq; Kr[e] = kk; Vr[e] = vv;
    }
    {
        float* kdst = sK + i * ITEM_STRIDE + n * DIM;
        float* vdst = sV + i * ITEM_STRIDE + n * DIM;
        #pragma unroll
        for (int j = 0; j < 4; ++j) {
            float4 kk, vv;
            kk.x = Kr[4*j+0]; kk.y = Kr[4*j+1]; kk.z = Kr[4*j+2]; kk.w = Kr[4*j+3];
            vv.x = Vr[4*j+0]; vv.y = Vr[4*j+1]; vv.z = Vr[4*j+2]; vv.w = Vr[4*j+3];
            ((float4*)kdst)[j] = kk;
            ((float4*)vdst)[j] = vv;
        }
    }
    __syncthreads();

    float sc[SEQ];
    #pragma unroll
    for (int m = 0; m < SEQ; ++m) {
        const float* kr = sK + i * ITEM_STRIDE + m * DIM;
        float s = 0.f;
        #pragma unroll
        for (int d = 0; d < DIM; ++d) s += Q[d] * kr[d];
        sc[m] = s * 0.25f;
    }
    float mx = sc[0];
    #pragma unroll
    for (int m = 1; m < SEQ; ++m) mx = fmaxf(mx, sc[m]);
    float sum = 0.f;
    #pragma unroll
    for (int m = 0; m < SEQ; ++m) { sc[m] = __expf(sc[m] - mx); sum += sc[m]; }
    const float inv = 1.0f / sum;

    float at[DIM];
    #pragma unroll
    for (int d = 0; d < DIM; ++d) at[d] = 0.f;
    #pragma unroll
    for (int m = 0; m < SEQ; ++m) {
        const float w = sc[m] * inv;
        const float* vr = sV + i * ITEM_STRIDE + m * DIM;
        #pragma unroll
        for (int d = 0; d < DIM; ++d) at[d] += w * vr[d];
    }

    float X1[DIM];
    #pragma unroll
    for (int e = 0; e < DIM; ++e) {
        float o = bo[e];
        #pragma unroll
        for (int d = 0; d < DIM; ++d) o += at[d] * Wo[d * DIM + e];
        X1[e] = X[e] + o;
    }
    float h[FF];
    #pragma unroll
    for (int f = 0; f < FF; ++f) {
        float a = b1[f];
        #pragma unroll
        for (int d = 0; d < DIM; ++d) a += X1[d] * W1[d * FF + f];
        h[f] = fmaxf(a, 0.f);
    }
    float X2[DIM];
    #pragma unroll
    for (int e = 0; e < DIM; ++e) {
        float a = b2[e];
        #pragma unroll
        for (int f = 0; f < FF; ++f) a += h[f] * W2[f * DIM + e];
        X2[e] = X1[e] + a;
    }

    __syncthreads();
    {
        float* xdst = sK + i * ITEM_STRIDE + n * DIM;
        #pragma unroll
        for (int j = 0; j < 4; ++j) {
            float4 xx;
            xx.x = X2[4*j+0]; xx.y = X2[4*j+1]; xx.z = X2[4*j+2]; xx.w = X2[4*j+3];
            ((float4*)xdst)[j] = xx;
        }
    }
    __syncthreads();

    float wh[DIM];
    #pragma unroll
    for (int d = 0; d < DIM; ++d) wh[d] = Wh[d * VOCAB + tid];
    const float bhv = bh[tid];

    const size_t obase = (size_t)blockIdx.x * (ITEMS_PER_BLOCK * SEQ) * VOCAB + tid;
    #pragma unroll 4
    for (int r = 0; r < ITEMS_PER_BLOCK * SEQ; ++r) {
        const float* xr = sK + (r >> 3) * ITEM_STRIDE + (r & 7) * DIM;
        float acc = bhv;
        #pragma unroll
        for (int d = 0; d < DIM; ++d) acc += xr[d] * wh[d];
        out[obase + (size_t)r * VOCAB] = acc;
    }
}

extern "C" void kernel_launch(void* const* d_in, const int* in_sizes, int n_in,
                              void* d_out, int out_size, void* d_ws, size_t ws_size,
                              hipStream_t stream) {
    const int*   x           = (const int*)  d_in[0];
    const float* token_embed = (const float*)d_in[1];
    const float* pos_embed   = (const float*)d_in[2];
    const float* Wq = (const float*)d_in[3];
    const float* bq = (const float*)d_in[4];
    const float* Wk = (const float*)d_in[5];
    const float* bk = (const float*)d_in[6];
    const float* Wv = (const float*)d_in[7];
    const float* bv = (const float*)d_in[8];
    const float* Wo = (const float*)d_in[9];
    const float* bo = (const float*)d_in[10];
    const float* W1 = (const float*)d_in[11];
    const float* b1 = (const float*)d_in[12];
    const float* W2 = (const float*)d_in[13];
    const float* b2 = (const float*)d_in[14];
    const float* Wh = (const float*)d_in[15];
    const float* bh = (const float*)d_in[16];
    float* out = (float*)d_out;

    const int B = in_sizes[0] / SEQ;                 // 32768
    const int nrows = B * SEQ;                       // 262144
    const size_t ws_needed = (size_t)nrows * DIM * sizeof(float);  // 16 MB

    if (ws_size >= ws_needed) {
        float* xws = (float*)d_ws;
        body_kernel<<<(nrows / 2) / 256, 256, 0, stream>>>(
            x, token_embed, pos_embed, Wq, bq, Wk, bk, Wv, bv, Wo, bo,
            W1, b1, W2, b2, xws, nrows / 2);
        head_kernel<<<nrows / ROWS_PER_BLOCK, 256, 0, stream>>>(
            xws, Wh, bh, out);
    } else {
        fused_fallback_kernel<<<B / ITEMS_PER_BLOCK, 256, 0, stream>>>(
            x, token_embed, pos_embed, Wq, bq, Wk, bk, Wv, bv, Wo, bo,
            W1, b1, W2, b2, Wh, bh, out);
    }
}